// Round 2
// baseline (198.814 us; speedup 1.0000x reference)
//
#include <hip/hip_runtime.h>

// LoRA linear: out = x @ (W + 2*B@A)^T + b
//   Kernel 0: sniff input dtype (bf16 vs fp32) -> flag in d_ws
//   Kernel 1: fold rank-16 update: Weff = W + 2*B@A   (bf16, in d_ws)
//   Kernel 2: 128x128x32 MFMA GEMM (16x16x32 bf16), conservative staging:
//             plain vector loads + ds_write_b128, padded LDS (no swizzle,
//             no global_load_lds) -- correctness-first structure.

typedef __bf16 bf16x8 __attribute__((ext_vector_type(8)));
typedef float f32x4 __attribute__((ext_vector_type(4)));
typedef unsigned short ushort8 __attribute__((ext_vector_type(8)));  // 16B

__device__ __forceinline__ float bf2f(unsigned short h) {
    union { unsigned int u; float f; } v; v.u = ((unsigned int)h) << 16; return v.f;
}
__device__ __forceinline__ unsigned short f2bf(float f) {
    union { float ff; unsigned int u; } v; v.ff = f;
    unsigned int u = v.u;
    return (unsigned short)((u + 0x7FFFu + ((u >> 16) & 1u)) >> 16);  // RNE
}
__device__ __forceinline__ ushort8 cvt8(f32x4 a, f32x4 b) {
    ushort8 o;
#pragma unroll
    for (int i = 0; i < 4; ++i) { o[i] = f2bf(a[i]); o[i + 4] = f2bf(b[i]); }
    return o;
}

// ---------- Kernel 0: dtype sniffer ----------
// W values are tiny (|W| <~ 0.12): stored-bf16 => every ushort has exp<=~123.
// stored-fp32 => even-index ushorts are mantissa halves, ~41% have exp>=150.
__global__ void sniff_dtype(const unsigned short* __restrict__ w, int* __restrict__ flag) {
    int i = threadIdx.x;  // 64 threads, 1 wave
    int cnt = 0;
    for (int j = i; j < 256; j += 64) {
        int e = (w[2 * j] >> 7) & 0xFF;
        cnt += (e >= 150) ? 1 : 0;
    }
#pragma unroll
    for (int off = 32; off > 0; off >>= 1) cnt += __shfl_down(cnt, off, 64);
    if (i == 0) *flag = (cnt >= 16) ? 1 : 0;  // 1 = fp32 inputs
}

// ---------- Kernel 1: Weff = W + 2 * B @ A ----------
__global__ __launch_bounds__(256) void make_weff(
    const void* __restrict__ W_, const void* __restrict__ A_,
    const void* __restrict__ B_, unsigned short* __restrict__ Weff,
    const int* __restrict__ flagp)
{
    const int flag = *flagp;
    int idx = blockIdx.x * 256 + threadIdx.x;  // 0..131071
    int o  = idx >> 7;                          // 0..1023
    int kc = (idx & 127) << 3;                  // k chunk of 8

    float br[16], acc8[8];
    if (flag) {  // fp32 inputs
        const float* W = (const float*)W_;
        const float* A = (const float*)A_;
        const float* B = (const float*)B_;
#pragma unroll
        for (int r = 0; r < 16; ++r) br[r] = 2.0f * B[o * 16 + r];
#pragma unroll
        for (int j = 0; j < 8; ++j) acc8[j] = W[(size_t)o * 1024 + kc + j];
#pragma unroll
        for (int r = 0; r < 16; ++r)
#pragma unroll
            for (int j = 0; j < 8; ++j) acc8[j] += br[r] * A[r * 1024 + kc + j];
    } else {     // bf16 inputs
        const unsigned short* W = (const unsigned short*)W_;
        const unsigned short* A = (const unsigned short*)A_;
        const unsigned short* B = (const unsigned short*)B_;
#pragma unroll
        for (int r = 0; r < 16; ++r) br[r] = 2.0f * bf2f(B[o * 16 + r]);
#pragma unroll
        for (int j = 0; j < 8; ++j) acc8[j] = bf2f(W[(size_t)o * 1024 + kc + j]);
#pragma unroll
        for (int r = 0; r < 16; ++r)
#pragma unroll
            for (int j = 0; j < 8; ++j) acc8[j] += br[r] * bf2f(A[r * 1024 + kc + j]);
    }
#pragma unroll
    for (int j = 0; j < 8; ++j) Weff[(size_t)o * 1024 + kc + j] = f2bf(acc8[j]);
}

// ---------- Kernel 2: out = X @ Weff^T + b ----------
// BM=BN=128, BK=32, 256 threads = 4 waves, each wave one 64x64 quadrant.
// LDS rows padded to 40 ushorts (80 B): 16B-aligned slots, <=2-way bank aliasing.
#define LDW 40

__global__ __launch_bounds__(256) void gemm_bt(
    const void* __restrict__ X_,               // [M][1024] bf16 or fp32
    const unsigned short* __restrict__ Wt,     // [1024][1024] bf16 (Weff)
    const void* __restrict__ bias_,            // [1024]
    void* __restrict__ out_,                   // [M][1024]
    const int* __restrict__ flagp)
{
    __shared__ __align__(16) unsigned short lA[128 * LDW];
    __shared__ __align__(16) unsigned short lB[128 * LDW];

    const int flag = *flagp;
    const int t    = threadIdx.x;
    const int lane = t & 63;
    const int w    = t >> 6;
    const int bm   = blockIdx.x * 128;
    const int bn   = blockIdx.y * 128;
    const int wm   = (w & 1) * 64;
    const int wn   = (w >> 1) * 64;
    const int r16  = lane & 15;
    const int quad = lane >> 4;

    // staging map: thread t owns (row r0, slot s0) and (row r0+64, slot s0); 16B each
    const int r0 = t >> 2;        // 0..63
    const int s0 = t & 3;         // k-chunk of 8
    const size_t gxa0 = (size_t)(bm + r0) * 1024 + s0 * 8;
    const size_t gxa1 = (size_t)(bm + r0 + 64) * 1024 + s0 * 8;
    const size_t gwb0 = (size_t)(bn + r0) * 1024 + s0 * 8;
    const size_t gwb1 = (size_t)(bn + r0 + 64) * 1024 + s0 * 8;
    unsigned short* sa0 = lA + r0 * LDW + s0 * 8;
    unsigned short* sa1 = lA + (r0 + 64) * LDW + s0 * 8;
    unsigned short* sb0 = lB + r0 * LDW + s0 * 8;
    unsigned short* sb1 = lB + (r0 + 64) * LDW + s0 * 8;

    const int aoff = (wm + r16) * LDW + quad * 8;
    const int boff = (wn + r16) * LDW + quad * 8;

    f32x4 acc[4][4];
#pragma unroll
    for (int i = 0; i < 4; ++i)
#pragma unroll
        for (int j = 0; j < 4; ++j) {
            f32x4 z = {0.f, 0.f, 0.f, 0.f};
            acc[i][j] = z;
        }

    const unsigned short* Xb = (const unsigned short*)X_;
    const float*          Xf = (const float*)X_;

    for (int kt = 0; kt < 1024; kt += 32) {
        // --- stage B (always bf16) ---
        *(ushort8*)sb0 = *(const ushort8*)(Wt + gwb0 + kt);
        *(ushort8*)sb1 = *(const ushort8*)(Wt + gwb1 + kt);
        // --- stage A (dtype-dependent) ---
        if (flag) {
            f32x4 a0 = *(const f32x4*)(Xf + gxa0 + kt);
            f32x4 a1 = *(const f32x4*)(Xf + gxa0 + kt + 4);
            f32x4 a2 = *(const f32x4*)(Xf + gxa1 + kt);
            f32x4 a3 = *(const f32x4*)(Xf + gxa1 + kt + 4);
            *(ushort8*)sa0 = cvt8(a0, a1);
            *(ushort8*)sa1 = cvt8(a2, a3);
        } else {
            *(ushort8*)sa0 = *(const ushort8*)(Xb + gxa0 + kt);
            *(ushort8*)sa1 = *(const ushort8*)(Xb + gxa1 + kt);
        }
        __syncthreads();

        bf16x8 fa[4], fb[4];
#pragma unroll
        for (int mt = 0; mt < 4; ++mt) fa[mt] = *(const bf16x8*)(lA + aoff + mt * 16 * LDW);
#pragma unroll
        for (int nt = 0; nt < 4; ++nt) fb[nt] = *(const bf16x8*)(lB + boff + nt * 16 * LDW);

#pragma unroll
        for (int mt = 0; mt < 4; ++mt)
#pragma unroll
            for (int nt = 0; nt < 4; ++nt)
                acc[mt][nt] = __builtin_amdgcn_mfma_f32_16x16x32_bf16(
                    fa[mt], fb[nt], acc[mt][nt], 0, 0, 0);

        __syncthreads();
    }

    // --- epilogue: C/D layout col=lane&15, row=quad*4+reg (m89-verified) ---
    const int orow0 = bm + wm + quad * 4;
    const int ocol0 = bn + wn + r16;
    if (flag) {
        const float* bias = (const float*)bias_;
        float*       out  = (float*)out_;
#pragma unroll
        for (int nt = 0; nt < 4; ++nt) {
            const float bv = bias[ocol0 + nt * 16];
#pragma unroll
            for (int mt = 0; mt < 4; ++mt)
#pragma unroll
                for (int i = 0; i < 4; ++i)
                    out[(size_t)(orow0 + mt * 16 + i) * 1024 + (ocol0 + nt * 16)] =
                        acc[mt][nt][i] + bv;
        }
    } else {
        const unsigned short* bias = (const unsigned short*)bias_;
        unsigned short*       out  = (unsigned short*)out_;
#pragma unroll
        for (int nt = 0; nt < 4; ++nt) {
            const float bv = bf2f(bias[ocol0 + nt * 16]);
#pragma unroll
            for (int mt = 0; mt < 4; ++mt)
#pragma unroll
                for (int i = 0; i < 4; ++i)
                    out[(size_t)(orow0 + mt * 16 + i) * 1024 + (ocol0 + nt * 16)] =
                        f2bf(acc[mt][nt][i] + bv);
        }
    }
}

extern "C" void kernel_launch(void* const* d_in, const int* in_sizes, int n_in,
                              void* d_out, int out_size, void* d_ws, size_t ws_size,
                              hipStream_t stream) {
    const void* x  = d_in[0];   // [M][1024]
    const void* W  = d_in[1];   // [1024][1024]
    const void* b  = d_in[2];   // [1024]
    const void* A  = d_in[3];   // [16][1024]
    const void* Bm = d_in[4];   // [1024][16]

    int* flag = (int*)d_ws;
    unsigned short* Weff = (unsigned short*)((char*)d_ws + 256);  // 2 MiB

    const int M = in_sizes[0] / 1024;  // 16384 (element count, dtype-independent)

    hipLaunchKernelGGL(sniff_dtype, dim3(1), dim3(64), 0, stream,
                       (const unsigned short*)W, flag);
    hipLaunchKernelGGL(make_weff, dim3(512), dim3(256), 0, stream,
                       W, A, Bm, Weff, flag);
    dim3 grid(M / 128, 1024 / 128);
    hipLaunchKernelGGL(gemm_bt, grid, dim3(256), 0, stream,
                       x, Weff, b, d_out, flag);
}

// Round 3
// 165.590 us; speedup vs baseline: 1.2006x; 1.2006x over previous
//
#include <hip/hip_runtime.h>

// LoRA linear, fp32 in/out (confirmed R2: WRITE_SIZE=64MB): out = x @ (W + 2*B@A)^T + b
//   Kernel prep: [blocks 0..511]  Weff = bf16(W + 2*B@A)      (2 MiB in ws)
//                [blocks 512.. ]  xbf  = bf16(x)              (32 MiB in ws)
//   Kernel gemm: m97-structure 128x128x32 bf16 MFMA GEMM, global_load_lds w=16
//                both operands, XOR k-chunk swizzle (<=2-way LDS bank aliasing),
//                fp32 bias + fp32 output epilogue.
//   Fallback (ws too small for xbf): same GEMM, A staged via fp32 loads + HW cvt.

typedef __bf16 bf16x8 __attribute__((ext_vector_type(8)));
typedef float f32x4 __attribute__((ext_vector_type(4)));
typedef unsigned short ushort8 __attribute__((ext_vector_type(8)));  // 16B

__device__ __forceinline__ unsigned short f2bf(float f) {
    __bf16 h = (__bf16)f;                       // HW RNE convert
    union { __bf16 b; unsigned short u; } v; v.b = h; return v.u;
}
__device__ __forceinline__ ushort8 cvt8(f32x4 a, f32x4 b) {
    ushort8 o;
#pragma unroll
    for (int i = 0; i < 4; ++i) { o[i] = f2bf(a[i]); o[i + 4] = f2bf(b[i]); }
    return o;
}
__device__ __forceinline__ void gld16(const unsigned short* g, unsigned short* l) {
    __builtin_amdgcn_global_load_lds(
        (const __attribute__((address_space(1))) unsigned int*)g,
        (__attribute__((address_space(3))) unsigned int*)l, 16, 0, 0);
}

// ---------------- prep: Weff fold + x conversion ----------------
__global__ __launch_bounds__(256) void prep(
    const float* __restrict__ X, const float* __restrict__ W,
    const float* __restrict__ A, const float* __restrict__ B,
    unsigned short* __restrict__ xbf, unsigned short* __restrict__ Weff)
{
    const int b = blockIdx.x;
    if (b < 512) {
        // Weff = bf16(W + 2*B@A): 131072 threads, 8 outputs each
        const int idx = b * 256 + threadIdx.x;
        const int o  = idx >> 7;
        const int kc = (idx & 127) << 3;
        float br[16];
#pragma unroll
        for (int r = 0; r < 16; ++r) br[r] = 2.0f * B[o * 16 + r];
        float acc[8];
        const float* wrow = W + (size_t)o * 1024 + kc;
#pragma unroll
        for (int j = 0; j < 8; ++j) acc[j] = wrow[j];
#pragma unroll
        for (int r = 0; r < 16; ++r) {
            const float* arow = A + r * 1024 + kc;
#pragma unroll
            for (int j = 0; j < 8; ++j) acc[j] += br[r] * arow[j];
        }
        ushort8 o8;
#pragma unroll
        for (int j = 0; j < 8; ++j) o8[j] = f2bf(acc[j]);
        *(ushort8*)(Weff + (size_t)o * 1024 + kc) = o8;
    } else {
        // xbf = bf16(x): 8 floats / thread
        const size_t i = ((size_t)(b - 512) * 256 + threadIdx.x) * 8;
        f32x4 a = *(const f32x4*)(X + i);
        f32x4 c = *(const f32x4*)(X + i + 4);
        *(ushort8*)(xbf + i) = cvt8(a, c);
    }
}

// ---------------- gemm: out = X @ Weff^T + b ----------------
// BM=BN=128, BK=32, 256 thr = 4 waves (64x64 quadrant each, 4x4 MFMA tiles).
// LDS linear [128][32] bf16 (global_load_lds needs lane-contiguous dest);
// k-chunk position XOR-swizzled by (row>>1)&3 on the GLOBAL source side.
template <bool XF32>
__global__ __launch_bounds__(256) void gemm_bt(
    const void* __restrict__ X_,               // bf16 [M][1024] (or fp32 fallback)
    const unsigned short* __restrict__ Wt,     // bf16 Weff [1024][1024]
    const float* __restrict__ bias,            // fp32 [1024]
    float* __restrict__ out)                   // fp32 [M][1024]
{
    __shared__ __align__(16) unsigned short lA[128 * 32];
    __shared__ __align__(16) unsigned short lB[128 * 32];

    const int t    = threadIdx.x;
    const int lane = t & 63;
    const int w    = t >> 6;
    const int bm   = blockIdx.x * 128;
    const int bn   = blockIdx.y * 128;
    const int wm   = (w & 1) * 64;
    const int wn   = (w >> 1) * 64;
    const int r16  = lane & 15;
    const int quad = lane >> 4;

    // staging: thread t -> LDS byte offset t*16 (wave-uniform + lane*16);
    // source k-chunk swizzled so reader's ds_read_b128 is <=2-way per 16 lanes.
    const int srow = t >> 2;                       // tile row 0..63 (+64 on 2nd)
    const int gc   = (t & 3) ^ ((srow >> 1) & 3);  // swizzled global k-chunk
    unsigned short* lsA = lA + t * 8;
    unsigned short* lsB = lB + t * 8;
    const size_t ga0 = (size_t)(bm + srow) * 1024 + gc * 8;
    const size_t ga1 = (size_t)(bm + srow + 64) * 1024 + gc * 8;
    const unsigned short* gB0 = Wt + (size_t)(bn + srow) * 1024 + gc * 8;

    // reader un-swizzle: chunk quad lives at position quad ^ ((row>>1)&3)
    const int p    = (quad ^ ((r16 >> 1) & 3)) * 8;
    const int aoff = (wm + r16) * 32 + p;
    const int boff = (wn + r16) * 32 + p;

    const unsigned short* Xb = (const unsigned short*)X_;
    const float*          Xf = (const float*)X_;

    f32x4 acc[4][4];
#pragma unroll
    for (int i = 0; i < 4; ++i)
#pragma unroll
        for (int j = 0; j < 4; ++j) {
            f32x4 z = {0.f, 0.f, 0.f, 0.f};
            acc[i][j] = z;
        }

    for (int kt = 0; kt < 1024; kt += 32) {
        if (XF32) {
            f32x4 a0 = *(const f32x4*)(Xf + ga0 + kt);
            f32x4 a1 = *(const f32x4*)(Xf + ga0 + kt + 4);
            f32x4 a2 = *(const f32x4*)(Xf + ga1 + kt);
            f32x4 a3 = *(const f32x4*)(Xf + ga1 + kt + 4);
            *(ushort8*)lsA          = cvt8(a0, a1);
            *(ushort8*)(lsA + 2048) = cvt8(a2, a3);
        } else {
            gld16(Xb + ga0 + kt, lsA);
            gld16(Xb + ga1 + kt, lsA + 2048);
        }
        gld16(gB0 + kt,             lsB);
        gld16(gB0 + kt + 64 * 1024, lsB + 2048);
        __syncthreads();   // drains vmcnt+lgkmcnt -> tiles ready

        bf16x8 fa[4], fb[4];
#pragma unroll
        for (int mt = 0; mt < 4; ++mt) fa[mt] = *(const bf16x8*)(lA + aoff + mt * 16 * 32);
#pragma unroll
        for (int nt = 0; nt < 4; ++nt) fb[nt] = *(const bf16x8*)(lB + boff + nt * 16 * 32);

#pragma unroll
        for (int mt = 0; mt < 4; ++mt)
#pragma unroll
            for (int nt = 0; nt < 4; ++nt)
                acc[mt][nt] = __builtin_amdgcn_mfma_f32_16x16x32_bf16(
                    fa[mt], fb[nt], acc[mt][nt], 0, 0, 0);

        __syncthreads();
    }

    // epilogue: C/D layout col=lane&15, row=quad*4+reg (R2-verified end-to-end)
    const int orow0 = bm + wm + quad * 4;
    const int ocol0 = bn + wn + r16;
#pragma unroll
    for (int nt = 0; nt < 4; ++nt) {
        const float bv = bias[ocol0 + nt * 16];
#pragma unroll
        for (int mt = 0; mt < 4; ++mt)
#pragma unroll
            for (int i = 0; i < 4; ++i)
                out[(size_t)(orow0 + mt * 16 + i) * 1024 + (ocol0 + nt * 16)] =
                    acc[mt][nt][i] + bv;
    }
}

extern "C" void kernel_launch(void* const* d_in, const int* in_sizes, int n_in,
                              void* d_out, int out_size, void* d_ws, size_t ws_size,
                              hipStream_t stream) {
    const float* x  = (const float*)d_in[0];   // [M][1024]
    const float* W  = (const float*)d_in[1];   // [1024][1024]
    const float* b  = (const float*)d_in[2];   // [1024]
    const float* A  = (const float*)d_in[3];   // [16][1024]
    const float* Bm = (const float*)d_in[4];   // [1024][16]
    float* out = (float*)d_out;

    const int M = in_sizes[0] / 1024;          // 16384
    dim3 grid(M / 128, 1024 / 128);

    const bool fast = ws_size >= ((size_t)(M)*1024*2 + (2u << 20) + 4096);
    if (fast) {
        unsigned short* xbf  = (unsigned short*)d_ws;
        unsigned short* Weff = xbf + (size_t)M * 1024;
        hipLaunchKernelGGL(prep, dim3(512 + M / 2), dim3(256), 0, stream,
                           x, W, A, Bm, xbf, Weff);
        hipLaunchKernelGGL((gemm_bt<false>), grid, dim3(256), 0, stream,
                           (const void*)xbf, Weff, b, out);
    } else {
        unsigned short* Weff = (unsigned short*)d_ws;
        hipLaunchKernelGGL(prep, dim3(512), dim3(256), 0, stream,
                           x, W, A, Bm, (unsigned short*)nullptr, Weff);
        hipLaunchKernelGGL((gemm_bt<true>), grid, dim3(256), 0, stream,
                           (const void*)x, Weff, b, out);
    }
}